// Round 8
// baseline (3089.417 us; speedup 1.0000x reference)
//
#include <hip/hip_runtime.h>
#include <stdint.h>

#define Bb   8
#define Nn   8192
#define CIN  64
#define COUT 128
#define Mm   2048
#define KNN  16
#define NTOT (Bb*Nn)   // 65536 rows

typedef unsigned long long ull;
typedef float v2f __attribute__((ext_vector_type(2)));

// ---------------- ws layout (bytes) ----------------
// h        : [0,         33554432)   float 65536x128
// nbr      : [33619968,  35717120)   int   8x2048x16
// stats    : [35717120,  35718144)   float sum[128], sumsq[128]
// sb       : [35718144,  35719168)   float scale[128], bias[128]
//
// LDS RULE (R2-R4 lesson): every workgroup's static LDS must stay
// <= 98,816 B. 131,072+ B silently fails to launch -> poison.

// ============================================================
// Packed f32 add/mul via inline asm (R7-proven bit-exact): IEEE
// RN per half, identical to __fadd_rn/__fmul_rn, immune to FMA
// contraction. Sub done as a + (-b) (sign flip exact).
// ============================================================
__device__ __forceinline__ v2f pk_add(v2f a, v2f b)
{ v2f d; asm("v_pk_add_f32 %0, %1, %2" : "=v"(d) : "v"(a), "v"(b)); return d; }
__device__ __forceinline__ v2f pk_mul(v2f a, v2f b)
{ v2f d; asm("v_pk_mul_f32 %0, %1, %2" : "=v"(d) : "v"(a), "v"(b)); return d; }

// ============================================================
// Wave64 float-max reduce (R6/R7-proven): 4x DPP row_shr within
// 16-lane rows, then readlane 15/31/47/63 + uniform u32 max
// (valid: distances >= 0, no -0/NaN).
// ============================================================
__device__ __forceinline__ float wave_max16(float x)
{
    int v = __float_as_int(x), t;
    t = __builtin_amdgcn_update_dpp(v, v, 0x111, 0xf, 0xf, false); // row_shr:1
    v = __float_as_int(fmaxf(__int_as_float(v), __int_as_float(t)));
    t = __builtin_amdgcn_update_dpp(v, v, 0x112, 0xf, 0xf, false); // row_shr:2
    v = __float_as_int(fmaxf(__int_as_float(v), __int_as_float(t)));
    t = __builtin_amdgcn_update_dpp(v, v, 0x114, 0xf, 0xf, false); // row_shr:4
    v = __float_as_int(fmaxf(__int_as_float(v), __int_as_float(t)));
    t = __builtin_amdgcn_update_dpp(v, v, 0x118, 0xf, 0xf, false); // row_shr:8
    v = __float_as_int(fmaxf(__int_as_float(v), __int_as_float(t)));
    unsigned r0 = (unsigned)__builtin_amdgcn_readlane(v, 15);
    unsigned r1 = (unsigned)__builtin_amdgcn_readlane(v, 31);
    unsigned r2 = (unsigned)__builtin_amdgcn_readlane(v, 47);
    unsigned r3 = (unsigned)__builtin_amdgcn_readlane(v, 63);
    unsigned m0 = r0 > r1 ? r0 : r1;
    unsigned m1 = r2 > r3 ? r2 : r3;
    unsigned mm = m0 > m1 ? m0 : m1;
    return __uint_as_float(mm);
}

// ============================================================
// MEGAKERNEL: blocks 0..7 = FPS (one per batch); blocks 8.. =
// gemm tiles (no fps dependency; rides free on idle CUs).
//
// FPS: 512 threads, 16 pts/thread BLOCKED (thread t owns
// [16t,16t+16) => lane order == index order). v_pk distance math
// (bitwise numpy-identical), DPP wave max + ballot, and a
// TAGGED-KEY LDS SPIN instead of s_barrier:
//   slot key = (m<<53) | (vbits<<21) | (8191-j)
// Tag per slot is monotone (a wave can't reach iteration m+2's
// write before every wave consumed m), so readiness check is
// min8(keys) >= (m<<53); double-buffered slots kill WAR; slots
// init to tag 0 (m starts at 1). Max over same-tag keys = max v,
// tie -> min j, matching reference argmax semantics.
// ============================================================
__global__ __launch_bounds__(512, 1)
void fps_gemm_kernel(const float* __restrict__ p1, float* __restrict__ p2out,
                     const float* __restrict__ x, const float* __restrict__ W,
                     float* __restrict__ h)
{
    __shared__ float px[Nn], py[Nn], pz[Nn];        // 96 KB
    __shared__ volatile ull wkey[2][8];             // + 128 B
    const int tid = threadIdx.x;

    if (blockIdx.x >= 8) {
        // -------- gemm path: h = x @ W^T, 4 rows/wave --------
        const int r0 = (blockIdx.x - 8) * 32 + (tid >> 6) * 4;
        const int cp = tid & 63;
        const float4* xp = (const float4*)(x + r0 * CIN);
        const float4* w0 = (const float4*)(W + (cp * 2) * CIN);
        const float4* w1 = (const float4*)(W + (cp * 2 + 1) * CIN);
        float a[4][2];
#pragma unroll
        for (int r = 0; r < 4; ++r) { a[r][0] = 0.f; a[r][1] = 0.f; }
#pragma unroll
        for (int k = 0; k < CIN / 4; ++k) {
            float4 wa = w0[k], wb = w1[k];
#pragma unroll
            for (int r = 0; r < 4; ++r) {
                float4 xv = xp[r * 16 + k];
                a[r][0] = fmaf(xv.x, wa.x, fmaf(xv.y, wa.y, fmaf(xv.z, wa.z, fmaf(xv.w, wa.w, a[r][0]))));
                a[r][1] = fmaf(xv.x, wb.x, fmaf(xv.y, wb.y, fmaf(xv.z, wb.z, fmaf(xv.w, wb.w, a[r][1]))));
            }
        }
#pragma unroll
        for (int r = 0; r < 4; ++r)
            *(float2*)(h + (r0 + r) * COUT + cp * 2) = make_float2(a[r][0], a[r][1]);
        return;
    }

    // ---------------- FPS path ----------------
    const int b    = blockIdx.x;
    const int lane = tid & 63, wid = tid >> 6;
    const float* pb = p1 + b * Nn * 3;

    if (tid < 16) ((volatile ull*)&wkey[0][0])[tid] = 0;   // tag 0 != any m>=1
    for (int i = tid; i < Nn * 3; i += 512) {
        float v = pb[i];
        int pt = i / 3;
        int c  = i - pt * 3;
        if (c == 0) px[pt] = v; else if (c == 1) py[pt] = v; else pz[pt] = v;
    }
    __syncthreads();   // staging barrier only

    v2f ppx[8], ppy[8], ppz[8], mind[8];
#pragma unroll
    for (int i = 0; i < 8; ++i) {
        int j0 = tid * 16 + 2 * i;
        ppx[i] = (v2f){px[j0], px[j0 + 1]};
        ppy[i] = (v2f){py[j0], py[j0 + 1]};
        ppz[i] = (v2f){pz[j0], pz[j0 + 1]};
        mind[i] = (v2f){1e10f, 1e10f};
    }

    float lx = px[0], ly = py[0], lz = pz[0];
    if (tid == 0) {
        int o = (b * Mm) * 3;
        p2out[o] = lx; p2out[o + 1] = ly; p2out[o + 2] = lz;
    }

    for (int m = 1; m < Mm; ++m) {
        const int buf = m & 1;
        float nx = -lx, ny = -ly, nz = -lz;     // exact sign flip
        v2f nx2 = (v2f){nx, nx}, ny2 = (v2f){ny, ny}, nz2 = (v2f){nz, nz};
        float bv0 = -1.0f, bv1 = -1.0f; int bj0 = 0, bj1 = 1;
#pragma unroll
        for (int i = 0; i < 8; ++i) {
            v2f dx = pk_add(ppx[i], nx2);       // == ppx - lx, bitwise
            v2f dy = pk_add(ppy[i], ny2);
            v2f dz = pk_add(ppz[i], nz2);
            v2f s  = pk_add(pk_add(pk_mul(dx, dx), pk_mul(dy, dy)),
                            pk_mul(dz, dz));    // ((dx2+dy2)+dz2)
            float m0 = fminf(mind[i].x, s.x);
            float m1 = fminf(mind[i].y, s.y);
            mind[i].x = m0; mind[i].y = m1;
            if (m0 > bv0) { bv0 = m0; bj0 = 2 * i; }
            if (m1 > bv1) { bv1 = m1; bj1 = 2 * i + 1; }
        }
        float bestv; int bestj;
        if (bv1 > bv0 || (bv1 == bv0 && bj1 < bj0)) { bestv = bv1; bestj = bj1; }
        else                                        { bestv = bv0; bestj = bj0; }
        bestj += tid * 16;

        float wv = wave_max16(bestv);
        ull tie = __ballot(bestv == wv);
        int low = __ffsll((long long)tie) - 1;   // lowest lane = lowest index
        const ull tagv = (ull)m << 53;
        if (lane == low) {
            wkey[buf][wid] = tagv | ((ull)__float_as_uint(wv) << 21) |
                             (ull)(8191 - bestj);
        }

        // spin until all 8 slots carry tag m (monotone => >= is ==)
        ull k[8], mn;
        do {
#pragma unroll
            for (int w = 0; w < 8; ++w) k[w] = wkey[buf][w];
            mn = k[0];
#pragma unroll
            for (int w = 1; w < 8; ++w) mn = k[w] < mn ? k[w] : mn;
        } while (mn < tagv);
        ull fk = k[0];
#pragma unroll
        for (int w = 1; w < 8; ++w) fk = k[w] > fk ? k[w] : fk;

        int jw = 8191 - (int)(fk & 0x1FFFFF);
        lx = px[jw]; ly = py[jw]; lz = pz[jw];   // broadcast reads
        if (tid == 0) {
            int o = (b * Mm + m) * 3;
            p2out[o] = lx; p2out[o + 1] = ly; p2out[o + 2] = lz;
        }
    }
}

// ============================================================
// kNN top-16 (R5-R7 verbatim, passing): one wave per query,
// 3-plane LDS (98,304 B), per-lane branchless top-3 cache,
// sortable u64 keys tie-break lower index like lax.top_k.
// ============================================================
__device__ __forceinline__ ull d2key(
    float qx, float qy, float qz, float qn, float x, float y, float z, int j)
{
    float dot = __fadd_rn(__fadd_rn(__fmul_rn(qx, x), __fmul_rn(qy, y)),
                          __fmul_rn(qz, z));
    float cn  = __fadd_rn(__fadd_rn(__fmul_rn(x, x), __fmul_rn(y, y)),
                          __fmul_rn(z, z));
    float d2  = __fadd_rn(__fsub_rn(qn, __fadd_rn(dot, dot)), cn);
    unsigned int bits = __float_as_uint(d2);
    unsigned int u = bits ^ (((unsigned int)((int)bits >> 31)) | 0x80000000u);
    return ((ull)u << 32) | (unsigned int)j;
}

__global__ __launch_bounds__(1024, 1)
void topk_kernel(const float* __restrict__ p1, const float* __restrict__ p2o,
                 int* __restrict__ nbr)
{
    __shared__ float px[Nn], py[Nn], pz[Nn];   // 96 KB
    const int tid   = threadIdx.x;
    const int b     = blockIdx.x >> 7;
    const int mbase = (blockIdx.x & 127) << 4;
    const float* pb = p1 + b * Nn * 3;

    for (int i = tid; i < Nn * 3; i += 1024) {
        float v = pb[i];
        int pt = i / 3;
        int c  = i - pt * 3;
        if (c == 0) px[pt] = v; else if (c == 1) py[pt] = v; else pz[pt] = v;
    }
    __syncthreads();

    const int wid = tid >> 6, lane = tid & 63;
    const int qrow = b * Mm + mbase + wid;
    float qx = p2o[qrow * 3], qy = p2o[qrow * 3 + 1], qz = p2o[qrow * 3 + 2];
    float qn = __fadd_rn(__fadd_rn(__fmul_rn(qx, qx), __fmul_rn(qy, qy)),
                         __fmul_rn(qz, qz));

    const ull INV = ~0ull;
    ull k1 = INV, k2 = INV, k3 = INV;
#pragma unroll 4
    for (int i = 0; i < 128; ++i) {
        int j = lane + (i << 6);
        ull key = d2key(qx, qy, qz, qn, px[j], py[j], pz[j], j);
        bool b1 = key < k1, b2 = key < k2, b3 = key < k3;
        ull n1 = b1 ? key : k1;
        ull n2 = b1 ? k1 : (b2 ? key : k2);
        ull n3 = b2 ? k2 : (b3 ? key : k3);
        k1 = n1; k2 = n2; k3 = n3;
    }

    int* out = nbr + qrow * KNN;
    for (int r = 0; r < KNN; ++r) {
        ull wk = k1;
#pragma unroll
        for (int off = 1; off < 64; off <<= 1) {
            ull ok = __shfl_xor(wk, off, 64);
            wk = ok < wk ? ok : wk;
        }
        if (lane == 0) out[r] = (int)(unsigned int)(wk & 0xFFFFFFFFull);
        if (k1 == wk) { k1 = k2; k2 = k3; k3 = INV; }
        if (k1 == INV) {   // rare: rebuild top-3 among keys > wk
            for (int i = 0; i < 128; ++i) {
                int j = lane + (i << 6);
                ull key = d2key(qx, qy, qz, qn, px[j], py[j], pz[j], j);
                if (key > wk) {
                    bool b1 = key < k1, b2 = key < k2, b3 = key < k3;
                    ull n1 = b1 ? key : k1;
                    ull n2 = b1 ? k1 : (b2 ? key : k2);
                    ull n3 = b2 ? k2 : (b3 ? key : k3);
                    k1 = n1; k2 = n2; k3 = n3;
                }
            }
        }
    }
}

// ============================================================
// BN stats (R5-R7 verbatim).
// ============================================================
__global__ __launch_bounds__(256)
void stats_kernel(const float* __restrict__ h, float* __restrict__ stats)
{
    __shared__ float4 rs[256], rq[256];
    const int tid  = threadIdx.x;
    const int c4   = (tid & 31) * 4;
    const int rsub = tid >> 5;
    const int rbase = blockIdx.x * 256;
    float4 s = make_float4(0, 0, 0, 0), q = make_float4(0, 0, 0, 0);
    for (int i = 0; i < 32; ++i) {
        int r = rbase + rsub + i * 8;
        float4 v = *(const float4*)(h + r * COUT + c4);
        s.x += v.x; s.y += v.y; s.z += v.z; s.w += v.w;
        q.x = fmaf(v.x, v.x, q.x); q.y = fmaf(v.y, v.y, q.y);
        q.z = fmaf(v.z, v.z, q.z); q.w = fmaf(v.w, v.w, q.w);
    }
    rs[tid] = s; rq[tid] = q;
    __syncthreads();
    if (tid < 32) {
        for (int j = 1; j < 8; ++j) {
            float4 o = rs[tid + 32 * j];
            s.x += o.x; s.y += o.y; s.z += o.z; s.w += o.w;
            float4 oq = rq[tid + 32 * j];
            q.x += oq.x; q.y += oq.y; q.z += oq.z; q.w += oq.w;
        }
        atomicAdd(&stats[c4 + 0], s.x); atomicAdd(&stats[c4 + 1], s.y);
        atomicAdd(&stats[c4 + 2], s.z); atomicAdd(&stats[c4 + 3], s.w);
        atomicAdd(&stats[128 + c4 + 0], q.x); atomicAdd(&stats[128 + c4 + 1], q.y);
        atomicAdd(&stats[128 + c4 + 2], q.z); atomicAdd(&stats[128 + c4 + 3], q.w);
    }
}

__global__ void finalize_kernel(const float* __restrict__ stats,
                                const float* __restrict__ gamma,
                                const float* __restrict__ beta,
                                float* __restrict__ sb)
{
    int c = threadIdx.x;
    float mean = stats[c] * (1.0f / 65536.0f);
    float var  = stats[128 + c] * (1.0f / 65536.0f) - mean * mean;
    float scale = gamma[c] / sqrtf(var + 1e-5f);
    float bias  = beta[c] - mean * scale;
    sb[c] = scale; sb[128 + c] = bias;
}

// ============================================================
// Gather + BN affine + ReLU + max over K (R5-R7 verbatim).
// ============================================================
__global__ __launch_bounds__(256)
void gather_kernel(const float* __restrict__ h, const int* __restrict__ nbr,
                   const float* __restrict__ sb, float* __restrict__ y)
{
    const int wid = threadIdx.x >> 6, lane = threadIdx.x & 63;
    const int t4 = blockIdx.x * 4 + wid;    // == b*2048 + m
    const int b  = t4 >> 11;
    const int c0 = lane * 2;
    float s0 = sb[c0], s1 = sb[c0 + 1];
    float b0 = sb[128 + c0], b1 = sb[128 + c0 + 1];
    const int* nb = nbr + t4 * KNN;
    float a0 = -1e30f, a1 = -1e30f;
#pragma unroll
    for (int k = 0; k < KNN; ++k) {
        int idx = nb[k];
        float2 v = *(const float2*)(h + ((b << 13) + idx) * COUT + c0);
        a0 = fmaxf(a0, fmaf(v.x, s0, b0));
        a1 = fmaxf(a1, fmaf(v.y, s1, b1));
    }
    a0 = fmaxf(a0, 0.0f); a1 = fmaxf(a1, 0.0f);
    *(float2*)(y + t4 * COUT + c0) = make_float2(a0, a1);
}

extern "C" void kernel_launch(void* const* d_in, const int* in_sizes, int n_in,
                              void* d_out, int out_size, void* d_ws, size_t ws_size,
                              hipStream_t stream)
{
    const float* x     = (const float*)d_in[0];
    const float* p1    = (const float*)d_in[1];
    const float* W     = (const float*)d_in[2];
    const float* gamma = (const float*)d_in[3];
    const float* beta  = (const float*)d_in[4];

    float* y  = (float*)d_out;                       // (8,2048,128)
    float* p2 = (float*)d_out + Bb * Mm * COUT;      // (8,2048,3)

    char*  ws    = (char*)d_ws;
    float* h     = (float*)ws;
    int*   nbr   = (int*)(ws + 33619968);
    float* stats = (float*)(ws + 35717120);
    float* sb    = (float*)(ws + 35718144);

    hipMemsetAsync(stats, 0, 1024, stream);
    fps_gemm_kernel<<<8 + NTOT / 32, 512, 0, stream>>>(p1, p2, x, W, h);
    stats_kernel<<<256, 256, 0, stream>>>(h, stats);
    finalize_kernel<<<1, 128, 0, stream>>>(stats, gamma, beta, sb);
    topk_kernel<<<Bb * 128, 1024, 0, stream>>>(p1, p2, nbr);
    gather_kernel<<<Bb * Mm / 4, 256, 0, stream>>>(h, nbr, sb, y);
}

// Round 9
// 2096.724 us; speedup vs baseline: 1.4734x; 1.4734x over previous
//
#include <hip/hip_runtime.h>
#include <stdint.h>

#define Bb   8
#define Nn   8192
#define CIN  64
#define COUT 128
#define Mm   2048
#define KNN  16
#define NTOT (Bb*Nn)   // 65536 rows

typedef unsigned long long ull;
typedef float v2f __attribute__((ext_vector_type(2)));

#define MAGIC 0x55AA1234u

// ---------------- ws layout (bytes) ----------------
// h        : [0,         33554432)   float 65536x128
// idxpub   : [33619968,  33751040)   ull   8x2048  (magic<<32 | jw)
// stats    : [35717120,  35718144)   float sum[128], sumsq[128]
// sb       : [35718144,  35719168)   float scale[128], bias[128]
//
// LDS RULE (R2-R4 lesson): static LDS <= 98,816 B per WG.
// SYNC RULE (R8 lesson): s_barrier beats LDS spin by ~440 cyc/iter.

// ============================================================
// Packed f32 add/mul via inline asm (R7-proven bit-exact).
// ============================================================
__device__ __forceinline__ v2f pk_add(v2f a, v2f b)
{ v2f d; asm("v_pk_add_f32 %0, %1, %2" : "=v"(d) : "v"(a), "v"(b)); return d; }
__device__ __forceinline__ v2f pk_mul(v2f a, v2f b)
{ v2f d; asm("v_pk_mul_f32 %0, %1, %2" : "=v"(d) : "v"(a), "v"(b)); return d; }

// ============================================================
// Wave64 float-max reduce (R6/R7-proven).
// ============================================================
__device__ __forceinline__ float wave_max16(float x)
{
    int v = __float_as_int(x), t;
    t = __builtin_amdgcn_update_dpp(v, v, 0x111, 0xf, 0xf, false); // row_shr:1
    v = __float_as_int(fmaxf(__int_as_float(v), __int_as_float(t)));
    t = __builtin_amdgcn_update_dpp(v, v, 0x112, 0xf, 0xf, false); // row_shr:2
    v = __float_as_int(fmaxf(__int_as_float(v), __int_as_float(t)));
    t = __builtin_amdgcn_update_dpp(v, v, 0x114, 0xf, 0xf, false); // row_shr:4
    v = __float_as_int(fmaxf(__int_as_float(v), __int_as_float(t)));
    t = __builtin_amdgcn_update_dpp(v, v, 0x118, 0xf, 0xf, false); // row_shr:8
    v = __float_as_int(fmaxf(__int_as_float(v), __int_as_float(t)));
    unsigned r0 = (unsigned)__builtin_amdgcn_readlane(v, 15);
    unsigned r1 = (unsigned)__builtin_amdgcn_readlane(v, 31);
    unsigned r2 = (unsigned)__builtin_amdgcn_readlane(v, 47);
    unsigned r3 = (unsigned)__builtin_amdgcn_readlane(v, 63);
    unsigned m0 = r0 > r1 ? r0 : r1;
    unsigned m1 = r2 > r3 ? r2 : r3;
    unsigned mm = m0 > m1 ? m0 : m1;
    return __uint_as_float(mm);
}

// ============================================================
// d2 key for topk (R5-proven): sortable u64, tie -> lower index.
// ============================================================
__device__ __forceinline__ ull d2key(
    float qx, float qy, float qz, float qn, float x, float y, float z, int j)
{
    float dot = __fadd_rn(__fadd_rn(__fmul_rn(qx, x), __fmul_rn(qy, y)),
                          __fmul_rn(qz, z));
    float cn  = __fadd_rn(__fadd_rn(__fmul_rn(x, x), __fmul_rn(y, y)),
                          __fmul_rn(z, z));
    float d2  = __fadd_rn(__fsub_rn(qn, __fadd_rn(dot, dot)), cn);
    unsigned int bits = __float_as_uint(d2);
    unsigned int u = bits ^ (((unsigned int)((int)bits >> 31)) | 0x80000000u);
    return ((ull)u << 32) | (unsigned int)j;
}

// ============================================================
// MEGAKERNEL (256 blocks = 1/CU, all co-resident; 256 threads):
//  blocks 0..7   : FPS (R7-verbatim: 256 thr, packed math, DPP +
//                  ballot, single double-buffered barrier) + one
//                  agent-scope atomic publish of jw per iteration,
//                  issued right after jw extraction so the store
//                  ack hides under the ~550-cyc compute phase
//                  before the barrier drain.
//  blocks 8..255 : consumers, 31 per batch. Stage p1 planes in
//                  LDS, poll idxpub (poison 0xAA != MAGIC), query
//                  coords = planes[jw] (bitwise == p2), run R5-
//                  verbatim top-3 kNN per wave, fuse gather+BN+
//                  ReLU+max inline (h, sb from earlier kernels in
//                  the stream -> visibility via kernel boundary).
// Deadlock-free: consumers wait only on fps blocks (pure
// producers); grid == CU count with 1 block/CU.
// ============================================================
__global__ __launch_bounds__(256, 1)
void mega_kernel(const float* __restrict__ p1, float* __restrict__ p2out,
                 const float* __restrict__ h, const float* __restrict__ sb,
                 ull* idxpub, float* __restrict__ y)
{
    __shared__ float px[Nn], py[Nn], pz[Nn];        // 96 KB
    __shared__ alignas(16) ull wkey[2][4];          // + 64 B
    const int tid = threadIdx.x;

    if (blockIdx.x < 8) {
        // ---------------- FPS path (R7 verbatim + publish) ----------------
        const int b    = blockIdx.x;
        const int lane = tid & 63, wid = tid >> 6;
        const float* pb = p1 + b * Nn * 3;

        for (int i = tid; i < Nn * 3; i += 256) {
            float v = pb[i];
            int pt = i / 3;
            int c  = i - pt * 3;
            if (c == 0) px[pt] = v; else if (c == 1) py[pt] = v; else pz[pt] = v;
        }
        __syncthreads();

        v2f ppx[16], ppy[16], ppz[16], mind[16];
#pragma unroll
        for (int i = 0; i < 16; ++i) {
            int j0 = tid * 32 + 2 * i;
            ppx[i] = (v2f){px[j0], px[j0 + 1]};
            ppy[i] = (v2f){py[j0], py[j0 + 1]};
            ppz[i] = (v2f){pz[j0], pz[j0 + 1]};
            mind[i] = (v2f){1e10f, 1e10f};
        }

        float lx = px[0], ly = py[0], lz = pz[0];
        if (tid == 0) {
            __hip_atomic_store(&idxpub[b * Mm], ((ull)MAGIC << 32) | 0ull,
                               __ATOMIC_RELAXED, __HIP_MEMORY_SCOPE_AGENT);
            int o = (b * Mm) * 3;
            p2out[o] = lx; p2out[o + 1] = ly; p2out[o + 2] = lz;
        }

        for (int m = 1; m < Mm; ++m) {
            const int buf = m & 1;
            float nx = -lx, ny = -ly, nz = -lz;     // exact sign flip
            v2f nx2 = (v2f){nx, nx}, ny2 = (v2f){ny, ny}, nz2 = (v2f){nz, nz};
            float bv0 = -1.0f, bv1 = -1.0f; int bj0 = 0, bj1 = 1;
#pragma unroll
            for (int i = 0; i < 16; ++i) {
                v2f dx = pk_add(ppx[i], nx2);       // == ppx - lx, bitwise
                v2f dy = pk_add(ppy[i], ny2);
                v2f dz = pk_add(ppz[i], nz2);
                v2f s  = pk_add(pk_add(pk_mul(dx, dx), pk_mul(dy, dy)),
                                pk_mul(dz, dz));    // ((dx2+dy2)+dz2)
                float m0 = fminf(mind[i].x, s.x);
                float m1 = fminf(mind[i].y, s.y);
                mind[i].x = m0; mind[i].y = m1;
                if (m0 > bv0) { bv0 = m0; bj0 = 2 * i; }
                if (m1 > bv1) { bv1 = m1; bj1 = 2 * i + 1; }
            }
            float bestv; int bestj;
            if (bv1 > bv0 || (bv1 == bv0 && bj1 < bj0)) { bestv = bv1; bestj = bj1; }
            else                                        { bestv = bv0; bestj = bj0; }
            bestj += tid * 32;

            float wv = wave_max16(bestv);
            ull tie = __ballot(bestv == wv);
            int low = __ffsll((long long)tie) - 1;   // lowest lane = lowest index
            if (lane == low) {
                wkey[buf][wid] = ((ull)__float_as_uint(wv) << 32) |
                                 (unsigned int)(~(unsigned int)bestj);
            }
            __syncthreads();

            ull k0 = wkey[buf][0], k1 = wkey[buf][1];
            ull k2 = wkey[buf][2], k3 = wkey[buf][3];
            ull k01 = k0 > k1 ? k0 : k1;
            ull k23 = k2 > k3 ? k2 : k3;
            ull fk  = k01 > k23 ? k01 : k23;
            int jw = (int)(~(unsigned int)fk);
            // publish early: store-ack hides under the next iteration's
            // compute phase before the barrier drain
            if (tid == 0) {
                __hip_atomic_store(&idxpub[b * Mm + m],
                                   ((ull)MAGIC << 32) | (ull)(unsigned)jw,
                                   __ATOMIC_RELAXED, __HIP_MEMORY_SCOPE_AGENT);
            }
            lx = px[jw]; ly = py[jw]; lz = pz[jw];   // broadcast reads
            if (tid == 0) {
                int o = (b * Mm + m) * 3;
                p2out[o] = lx; p2out[o + 1] = ly; p2out[o + 2] = lz;
            }
        }
        return;
    }

    // ---------------- consumer path: fused kNN + gather ----------------
    const int cb = blockIdx.x - 8;      // 0..247
    const int b  = cb / 31;             // 31 blocks per batch
    const int k  = cb - b * 31;         // query residue mod 31
    const float* pb = p1 + b * Nn * 3;

    for (int i = tid; i < Nn * 3; i += 256) {
        float v = pb[i];
        int pt = i / 3;
        int c  = i - pt * 3;
        if (c == 0) px[pt] = v; else if (c == 1) py[pt] = v; else pz[pt] = v;
    }
    __syncthreads();

    const int w = tid >> 6, lane = tid & 63;
    const int c0 = lane * 2;
    const float s0 = sb[c0], s1 = sb[c0 + 1];
    const float bb0 = sb[128 + c0], bb1 = sb[128 + c0 + 1];
    const ull INV = ~0ull;

    for (int t = w; k + 31 * t < Mm; t += 4) {
        const int m = k + 31 * t;
        const int qrow = b * Mm + m;

        // poll until fps publishes this query's index
        ull pv;
        for (;;) {
            pv = __hip_atomic_load(&idxpub[qrow], __ATOMIC_RELAXED,
                                   __HIP_MEMORY_SCOPE_AGENT);
            if ((unsigned)(pv >> 32) == MAGIC) break;
            __builtin_amdgcn_s_sleep(2);
        }
        const int jq = (int)(pv & 0x1FFFull);
        const float qx = px[jq], qy = py[jq], qz = pz[jq];
        const float qn = __fadd_rn(__fadd_rn(__fmul_rn(qx, qx), __fmul_rn(qy, qy)),
                                   __fmul_rn(qz, qz));

        // R5-verbatim scan with per-lane top-3 cache
        ull k1 = INV, k2 = INV, k3 = INV;
#pragma unroll 4
        for (int i = 0; i < 128; ++i) {
            int j = lane + (i << 6);
            ull key = d2key(qx, qy, qz, qn, px[j], py[j], pz[j], j);
            bool b1 = key < k1, b2 = key < k2, b3 = key < k3;
            ull n1 = b1 ? key : k1;
            ull n2 = b1 ? k1 : (b2 ? key : k2);
            ull n3 = b2 ? k2 : (b3 ? key : k3);
            k1 = n1; k2 = n2; k3 = n3;
        }

        float a0 = -1e30f, a1 = -1e30f;
        for (int r = 0; r < KNN; ++r) {
            ull wk = k1;
#pragma unroll
            for (int off = 1; off < 64; off <<= 1) {
                ull ok = __shfl_xor(wk, off, 64);
                wk = ok < wk ? ok : wk;
            }
            const int n = (int)(unsigned int)(wk & 0xFFFFFFFFull);
            // issue gather load early; latency overlaps cache maintenance
            const float2 v = *(const float2*)(h + (((b << 13) + n) * COUT) + c0);
            if (k1 == wk) { k1 = k2; k2 = k3; k3 = INV; }
            if (k1 == INV) {   // rare: rebuild top-3 among keys > wk
                for (int i = 0; i < 128; ++i) {
                    int j = lane + (i << 6);
                    ull key = d2key(qx, qy, qz, qn, px[j], py[j], pz[j], j);
                    if (key > wk) {
                        bool b1 = key < k1, b2 = key < k2, b3 = key < k3;
                        ull n1 = b1 ? key : k1;
                        ull n2 = b1 ? k1 : (b2 ? key : k2);
                        ull n3 = b2 ? k2 : (b3 ? key : k3);
                        k1 = n1; k2 = n2; k3 = n3;
                    }
                }
            }
            a0 = fmaxf(a0, fmaf(v.x, s0, bb0));
            a1 = fmaxf(a1, fmaf(v.y, s1, bb1));
        }
        a0 = fmaxf(a0, 0.0f); a1 = fmaxf(a1, 0.0f);
        *(float2*)(y + qrow * COUT + c0) = make_float2(a0, a1);
    }
}

// ============================================================
// h = x @ W^T : 4 rows per wave (R5-R7 verbatim, passing).
// ============================================================
__global__ __launch_bounds__(256)
void gemm_kernel(const float* __restrict__ x, const float* __restrict__ W,
                 float* __restrict__ h)
{
    const int r0 = blockIdx.x * 16 + (threadIdx.x >> 6) * 4;
    const int cp = threadIdx.x & 63;
    const float4* xp = (const float4*)(x + r0 * CIN);
    const float4* w0 = (const float4*)(W + (cp * 2) * CIN);
    const float4* w1 = (const float4*)(W + (cp * 2 + 1) * CIN);
    float a[4][2];
#pragma unroll
    for (int r = 0; r < 4; ++r) { a[r][0] = 0.f; a[r][1] = 0.f; }
#pragma unroll
    for (int k = 0; k < CIN / 4; ++k) {
        float4 wa = w0[k], wb = w1[k];
#pragma unroll
        for (int r = 0; r < 4; ++r) {
            float4 xv = xp[r * 16 + k];
            a[r][0] = fmaf(xv.x, wa.x, fmaf(xv.y, wa.y, fmaf(xv.z, wa.z, fmaf(xv.w, wa.w, a[r][0]))));
            a[r][1] = fmaf(xv.x, wb.x, fmaf(xv.y, wb.y, fmaf(xv.z, wb.z, fmaf(xv.w, wb.w, a[r][1]))));
        }
    }
#pragma unroll
    for (int r = 0; r < 4; ++r)
        *(float2*)(h + (r0 + r) * COUT + cp * 2) = make_float2(a[r][0], a[r][1]);
}

// ============================================================
// BN stats (R5-R8 verbatim).
// ============================================================
__global__ __launch_bounds__(256)
void stats_kernel(const float* __restrict__ h, float* __restrict__ stats)
{
    __shared__ float4 rs[256], rq[256];
    const int tid  = threadIdx.x;
    const int c4   = (tid & 31) * 4;
    const int rsub = tid >> 5;
    const int rbase = blockIdx.x * 256;
    float4 s = make_float4(0, 0, 0, 0), q = make_float4(0, 0, 0, 0);
    for (int i = 0; i < 32; ++i) {
        int r = rbase + rsub + i * 8;
        float4 v = *(const float4*)(h + r * COUT + c4);
        s.x += v.x; s.y += v.y; s.z += v.z; s.w += v.w;
        q.x = fmaf(v.x, v.x, q.x); q.y = fmaf(v.y, v.y, q.y);
        q.z = fmaf(v.z, v.z, q.z); q.w = fmaf(v.w, v.w, q.w);
    }
    rs[tid] = s; rq[tid] = q;
    __syncthreads();
    if (tid < 32) {
        for (int j = 1; j < 8; ++j) {
            float4 o = rs[tid + 32 * j];
            s.x += o.x; s.y += o.y; s.z += o.z; s.w += o.w;
            float4 oq = rq[tid + 32 * j];
            q.x += oq.x; q.y += oq.y; q.z += oq.z; q.w += oq.w;
        }
        atomicAdd(&stats[c4 + 0], s.x); atomicAdd(&stats[c4 + 1], s.y);
        atomicAdd(&stats[c4 + 2], s.z); atomicAdd(&stats[c4 + 3], s.w);
        atomicAdd(&stats[128 + c4 + 0], q.x); atomicAdd(&stats[128 + c4 + 1], q.y);
        atomicAdd(&stats[128 + c4 + 2], q.z); atomicAdd(&stats[128 + c4 + 3], q.w);
    }
}

__global__ void finalize_kernel(const float* __restrict__ stats,
                                const float* __restrict__ gamma,
                                const float* __restrict__ beta,
                                float* __restrict__ sb)
{
    int c = threadIdx.x;
    float mean = stats[c] * (1.0f / 65536.0f);
    float var  = stats[128 + c] * (1.0f / 65536.0f) - mean * mean;
    float scale = gamma[c] / sqrtf(var + 1e-5f);
    float bias  = beta[c] - mean * scale;
    sb[c] = scale; sb[128 + c] = bias;
}

extern "C" void kernel_launch(void* const* d_in, const int* in_sizes, int n_in,
                              void* d_out, int out_size, void* d_ws, size_t ws_size,
                              hipStream_t stream)
{
    const float* x     = (const float*)d_in[0];
    const float* p1    = (const float*)d_in[1];
    const float* W     = (const float*)d_in[2];
    const float* gamma = (const float*)d_in[3];
    const float* beta  = (const float*)d_in[4];

    float* y  = (float*)d_out;                       // (8,2048,128)
    float* p2 = (float*)d_out + Bb * Mm * COUT;      // (8,2048,3)

    char*  ws     = (char*)d_ws;
    float* h      = (float*)ws;
    ull*   idxpub = (ull*)(ws + 33619968);
    float* stats  = (float*)(ws + 35717120);
    float* sb     = (float*)(ws + 35718144);

    hipMemsetAsync(stats, 0, 1024, stream);
    gemm_kernel<<<NTOT / 16, 256, 0, stream>>>(x, W, h);
    stats_kernel<<<256, 256, 0, stream>>>(h, stats);
    finalize_kernel<<<1, 128, 0, stream>>>(stats, gamma, beta, sb);
    mega_kernel<<<256, 256, 0, stream>>>(p1, p2, h, sb, idxpub, y);
}

// Round 10
// 2071.606 us; speedup vs baseline: 1.4913x; 1.0121x over previous
//
#include <hip/hip_runtime.h>
#include <stdint.h>

#define Bb   8
#define Nn   8192
#define CIN  64
#define COUT 128
#define Mm   2048
#define KNN  16
#define NTOT (Bb*Nn)   // 65536 rows
#define NCONS 248      // consumer blocks

typedef unsigned long long ull;
typedef float v2f __attribute__((ext_vector_type(2)));

#define MAGIC 0x55AA1234u

// ---------------- ws layout (bytes) ----------------
// h        : [0,         33554432)   float 65536x128
// idxpub   : [33619968,  33751040)   ull   8x2048  (magic<<32 | jw)
// stats    : [35717120,  35718144)   float sum[128], sumsq[128]
// done     : [35718144,  35718152)   uint  gemm-done counter
// memset covers [35717120, 35719168).
//
// LDS RULE (R2-R4): static LDS <= 98,816 B per WG.
// SYNC RULE (R8): s_barrier beats LDS spin by ~440 cyc/iter.

__device__ __forceinline__ v2f pk_add(v2f a, v2f b)
{ v2f d; asm("v_pk_add_f32 %0, %1, %2" : "=v"(d) : "v"(a), "v"(b)); return d; }
__device__ __forceinline__ v2f pk_mul(v2f a, v2f b)
{ v2f d; asm("v_pk_mul_f32 %0, %1, %2" : "=v"(d) : "v"(a), "v"(b)); return d; }

// Wave64 float-max reduce (R6/R7-proven).
__device__ __forceinline__ float wave_max16(float x)
{
    int v = __float_as_int(x), t;
    t = __builtin_amdgcn_update_dpp(v, v, 0x111, 0xf, 0xf, false); // row_shr:1
    v = __float_as_int(fmaxf(__int_as_float(v), __int_as_float(t)));
    t = __builtin_amdgcn_update_dpp(v, v, 0x112, 0xf, 0xf, false); // row_shr:2
    v = __float_as_int(fmaxf(__int_as_float(v), __int_as_float(t)));
    t = __builtin_amdgcn_update_dpp(v, v, 0x114, 0xf, 0xf, false); // row_shr:4
    v = __float_as_int(fmaxf(__int_as_float(v), __int_as_float(t)));
    t = __builtin_amdgcn_update_dpp(v, v, 0x118, 0xf, 0xf, false); // row_shr:8
    v = __float_as_int(fmaxf(__int_as_float(v), __int_as_float(t)));
    unsigned r0 = (unsigned)__builtin_amdgcn_readlane(v, 15);
    unsigned r1 = (unsigned)__builtin_amdgcn_readlane(v, 31);
    unsigned r2 = (unsigned)__builtin_amdgcn_readlane(v, 47);
    unsigned r3 = (unsigned)__builtin_amdgcn_readlane(v, 63);
    unsigned m0 = r0 > r1 ? r0 : r1;
    unsigned m1 = r2 > r3 ? r2 : r3;
    unsigned mm = m0 > m1 ? m0 : m1;
    return __uint_as_float(mm);
}

// d2 key for topk (R5-proven): sortable u64, tie -> lower index.
__device__ __forceinline__ ull d2key(
    float qx, float qy, float qz, float qn, float x, float y, float z, int j)
{
    float dot = __fadd_rn(__fadd_rn(__fmul_rn(qx, x), __fmul_rn(qy, y)),
                          __fmul_rn(qz, z));
    float cn  = __fadd_rn(__fadd_rn(__fmul_rn(x, x), __fmul_rn(y, y)),
                          __fmul_rn(z, z));
    float d2  = __fadd_rn(__fsub_rn(qn, __fadd_rn(dot, dot)), cn);
    unsigned int bits = __float_as_uint(d2);
    unsigned int u = bits ^ (((unsigned int)((int)bits >> 31)) | 0x80000000u);
    return ((ull)u << 32) | (unsigned int)j;
}

// ============================================================
// SINGLE MEGAKERNEL (256 blocks x 512 thr, 1/CU co-resident):
//  blocks 0..7   : FPS immediately (512 thr = 2 waves/SIMD for
//                  latency hiding; packed math; DPP+ballot;
//                  single double-buffered barrier; publish jw).
//  blocks 8..255 : Phase A = grid-strided gemm (4 rows/wave,
//                  stride 7936) + register stats accum -> LDS
//                  combine -> atomicAdd stats -> release-add
//                  done counter. Spin done==248 (acquire => h &
//                  stats visible), compute sb per-lane locally.
//                  Phase B = R9-proven fused kNN+gather consume.
// Deadlock-free: fps never waits; consumers signal before
// waiting; poll targets only fps-produced slots.
// ============================================================
__global__ __launch_bounds__(512, 1)
void mega_kernel(const float* __restrict__ p1, float* __restrict__ p2out,
                 const float* __restrict__ x, const float* __restrict__ W,
                 const float* __restrict__ gamma, const float* __restrict__ beta,
                 float* __restrict__ h, float* __restrict__ stats,
                 unsigned int* done, ull* idxpub, float* __restrict__ y)
{
    __shared__ float px[Nn], py[Nn], pz[Nn];        // 96 KB
    __shared__ alignas(16) ull wkey[2][8];          // + 128 B
    const int tid = threadIdx.x;
    const int w = tid >> 6, lane = tid & 63;

    if (blockIdx.x < 8) {
        // ---------------- FPS path ----------------
        const int b = blockIdx.x;
        const float* pb = p1 + b * Nn * 3;

        for (int i = tid; i < Nn * 3; i += 512) {
            float v = pb[i];
            int pt = i / 3;
            int c  = i - pt * 3;
            if (c == 0) px[pt] = v; else if (c == 1) py[pt] = v; else pz[pt] = v;
        }
        __syncthreads();

        v2f ppx[8], ppy[8], ppz[8], mind[8];
#pragma unroll
        for (int i = 0; i < 8; ++i) {
            int j0 = tid * 16 + 2 * i;               // blocked mapping
            ppx[i] = (v2f){px[j0], px[j0 + 1]};
            ppy[i] = (v2f){py[j0], py[j0 + 1]};
            ppz[i] = (v2f){pz[j0], pz[j0 + 1]};
            mind[i] = (v2f){1e10f, 1e10f};
        }

        float lx = px[0], ly = py[0], lz = pz[0];
        if (tid == 0) {
            __hip_atomic_store(&idxpub[b * Mm], ((ull)MAGIC << 32) | 0ull,
                               __ATOMIC_RELAXED, __HIP_MEMORY_SCOPE_AGENT);
            int o = (b * Mm) * 3;
            p2out[o] = lx; p2out[o + 1] = ly; p2out[o + 2] = lz;
        }

        for (int m = 1; m < Mm; ++m) {
            const int buf = m & 1;
            float nx = -lx, ny = -ly, nz = -lz;     // exact sign flip
            v2f nx2 = (v2f){nx, nx}, ny2 = (v2f){ny, ny}, nz2 = (v2f){nz, nz};
            float bv0 = -1.0f, bv1 = -1.0f; int bj0 = 0, bj1 = 1;
#pragma unroll
            for (int i = 0; i < 8; ++i) {
                v2f dx = pk_add(ppx[i], nx2);       // == ppx - lx, bitwise
                v2f dy = pk_add(ppy[i], ny2);
                v2f dz = pk_add(ppz[i], nz2);
                v2f s  = pk_add(pk_add(pk_mul(dx, dx), pk_mul(dy, dy)),
                                pk_mul(dz, dz));    // ((dx2+dy2)+dz2)
                float m0 = fminf(mind[i].x, s.x);
                float m1 = fminf(mind[i].y, s.y);
                mind[i].x = m0; mind[i].y = m1;
                if (m0 > bv0) { bv0 = m0; bj0 = 2 * i; }
                if (m1 > bv1) { bv1 = m1; bj1 = 2 * i + 1; }
            }
            float bestv; int bestj;
            if (bv1 > bv0 || (bv1 == bv0 && bj1 < bj0)) { bestv = bv1; bestj = bj1; }
            else                                        { bestv = bv0; bestj = bj0; }
            bestj += tid * 16;

            float wv = wave_max16(bestv);
            ull tie = __ballot(bestv == wv);
            int low = __ffsll((long long)tie) - 1;   // lowest lane = lowest index
            if (lane == low) {
                wkey[buf][w] = ((ull)__float_as_uint(wv) << 32) |
                               (unsigned int)(~(unsigned int)bestj);
            }
            __syncthreads();

            ull fk = wkey[buf][0];
#pragma unroll
            for (int q = 1; q < 8; ++q) { ull k = wkey[buf][q]; fk = k > fk ? k : fk; }
            int jw = (int)(~(unsigned int)fk);
            if (tid == 0) {
                __hip_atomic_store(&idxpub[b * Mm + m],
                                   ((ull)MAGIC << 32) | (ull)(unsigned)jw,
                                   __ATOMIC_RELAXED, __HIP_MEMORY_SCOPE_AGENT);
            }
            lx = px[jw]; ly = py[jw]; lz = pz[jw];   // broadcast reads
            if (tid == 0) {
                int o = (b * Mm + m) * 3;
                p2out[o] = lx; p2out[o + 1] = ly; p2out[o + 2] = lz;
            }
        }
        return;
    }

    // ============== consumer: Phase A = gemm + stats ==============
    const int cb = blockIdx.x - 8;      // 0..247
    const int cp = lane;                // channel pair = 2cp, 2cp+1
    {
        const float4* w0 = (const float4*)(W + (cp * 2) * CIN);
        const float4* w1 = (const float4*)(W + (cp * 2 + 1) * CIN);
        float s0 = 0.f, s1 = 0.f, q0 = 0.f, q1 = 0.f;
        for (int r0 = cb * 32 + w * 4; r0 < NTOT; r0 += NCONS * 32) {
            const float4* xp = (const float4*)(x + r0 * CIN);
            float a[4][2];
#pragma unroll
            for (int r = 0; r < 4; ++r) { a[r][0] = 0.f; a[r][1] = 0.f; }
#pragma unroll
            for (int k = 0; k < CIN / 4; ++k) {
                float4 wa = w0[k], wb = w1[k];
#pragma unroll
                for (int r = 0; r < 4; ++r) {
                    float4 xv = xp[r * 16 + k];
                    a[r][0] = fmaf(xv.x, wa.x, fmaf(xv.y, wa.y, fmaf(xv.z, wa.z, fmaf(xv.w, wa.w, a[r][0]))));
                    a[r][1] = fmaf(xv.x, wb.x, fmaf(xv.y, wb.y, fmaf(xv.z, wb.z, fmaf(xv.w, wb.w, a[r][1]))));
                }
            }
#pragma unroll
            for (int r = 0; r < 4; ++r) {
                *(float2*)(h + (r0 + r) * COUT + cp * 2) = make_float2(a[r][0], a[r][1]);
                s0 += a[r][0]; s1 += a[r][1];
                q0 = fmaf(a[r][0], a[r][0], q0); q1 = fmaf(a[r][1], a[r][1], q1);
            }
        }
        // LDS combine (reuse px plane; Phase B restages after barrier)
        float4* comb = (float4*)px;                  // [8][64]
        comb[w * 64 + cp] = make_float4(s0, s1, q0, q1);
        __syncthreads();
        if (tid < 64) {
            float4 t = comb[cp];
#pragma unroll
            for (int j = 1; j < 8; ++j) {
                float4 o = comb[j * 64 + cp];
                t.x += o.x; t.y += o.y; t.z += o.z; t.w += o.w;
            }
            atomicAdd(&stats[2 * cp], t.x);     atomicAdd(&stats[2 * cp + 1], t.y);
            atomicAdd(&stats[128 + 2 * cp], t.z); atomicAdd(&stats[128 + 2 * cp + 1], t.w);
        }
        __syncthreads();
        if (tid == 0) {
            __hip_atomic_fetch_add(done, 1u, __ATOMIC_RELEASE,
                                   __HIP_MEMORY_SCOPE_AGENT);
            while (__hip_atomic_load(done, __ATOMIC_ACQUIRE,
                                     __HIP_MEMORY_SCOPE_AGENT) < NCONS)
                __builtin_amdgcn_s_sleep(2);
        }
        __syncthreads();   // all h stores + stats adds now visible
    }

    // per-lane BN scale/bias (same formula as proven finalize)
    float sc0, sc1, bi0, bi1;
    {
        float mean0 = stats[2 * cp] * (1.0f / 65536.0f);
        float mean1 = stats[2 * cp + 1] * (1.0f / 65536.0f);
        float var0  = stats[128 + 2 * cp] * (1.0f / 65536.0f) - mean0 * mean0;
        float var1  = stats[128 + 2 * cp + 1] * (1.0f / 65536.0f) - mean1 * mean1;
        sc0 = gamma[2 * cp] / sqrtf(var0 + 1e-5f);
        sc1 = gamma[2 * cp + 1] / sqrtf(var1 + 1e-5f);
        bi0 = beta[2 * cp] - mean0 * sc0;
        bi1 = beta[2 * cp + 1] - mean1 * sc1;
    }

    // ============== consumer: Phase B = fused kNN + gather ==============
    const int b = cb / 31;              // 31 blocks per batch
    const int k = cb - b * 31;          // query residue mod 31
    const float* pb = p1 + b * Nn * 3;

    for (int i = tid; i < Nn * 3; i += 512) {
        float v = pb[i];
        int pt = i / 3;
        int c  = i - pt * 3;
        if (c == 0) px[pt] = v; else if (c == 1) py[pt] = v; else pz[pt] = v;
    }
    __syncthreads();

    const int c0 = lane * 2;
    const ull INV = ~0ull;

    for (int t = w; k + 31 * t < Mm; t += 8) {
        const int m = k + 31 * t;
        const int qrow = b * Mm + m;

        ull pv;
        for (;;) {
            pv = __hip_atomic_load(&idxpub[qrow], __ATOMIC_RELAXED,
                                   __HIP_MEMORY_SCOPE_AGENT);
            if ((unsigned)(pv >> 32) == MAGIC) break;
            __builtin_amdgcn_s_sleep(2);
        }
        const int jq = (int)(pv & 0x1FFFull);
        const float qx = px[jq], qy = py[jq], qz = pz[jq];
        const float qn = __fadd_rn(__fadd_rn(__fmul_rn(qx, qx), __fmul_rn(qy, qy)),
                                   __fmul_rn(qz, qz));

        ull k1 = INV, k2 = INV, k3 = INV;
#pragma unroll 4
        for (int i = 0; i < 128; ++i) {
            int j = lane + (i << 6);
            ull key = d2key(qx, qy, qz, qn, px[j], py[j], pz[j], j);
            bool b1 = key < k1, b2 = key < k2, b3 = key < k3;
            ull n1 = b1 ? key : k1;
            ull n2 = b1 ? k1 : (b2 ? key : k2);
            ull n3 = b2 ? k2 : (b3 ? key : k3);
            k1 = n1; k2 = n2; k3 = n3;
        }

        float a0 = -1e30f, a1 = -1e30f;
        for (int r = 0; r < KNN; ++r) {
            ull wk = k1;
#pragma unroll
            for (int off = 1; off < 64; off <<= 1) {
                ull ok = __shfl_xor(wk, off, 64);
                wk = ok < wk ? ok : wk;
            }
            const int n = (int)(unsigned int)(wk & 0xFFFFFFFFull);
            const float2 v = *(const float2*)(h + (((b << 13) + n) * COUT) + c0);
            if (k1 == wk) { k1 = k2; k2 = k3; k3 = INV; }
            if (k1 == INV) {   // rare: rebuild top-3 among keys > wk
                for (int i = 0; i < 128; ++i) {
                    int j = lane + (i << 6);
                    ull key = d2key(qx, qy, qz, qn, px[j], py[j], pz[j], j);
                    if (key > wk) {
                        bool b1 = key < k1, b2 = key < k2, b3 = key < k3;
                        ull n1 = b1 ? key : k1;
                        ull n2 = b1 ? k1 : (b2 ? key : k2);
                        ull n3 = b2 ? k2 : (b3 ? key : k3);
                        k1 = n1; k2 = n2; k3 = n3;
                    }
                }
            }
            a0 = fmaxf(a0, fmaf(v.x, sc0, bi0));
            a1 = fmaxf(a1, fmaf(v.y, sc1, bi1));
        }
        a0 = fmaxf(a0, 0.0f); a1 = fmaxf(a1, 0.0f);
        *(float2*)(y + qrow * COUT + c0) = make_float2(a0, a1);
    }
}

extern "C" void kernel_launch(void* const* d_in, const int* in_sizes, int n_in,
                              void* d_out, int out_size, void* d_ws, size_t ws_size,
                              hipStream_t stream)
{
    const float* x     = (const float*)d_in[0];
    const float* p1    = (const float*)d_in[1];
    const float* W     = (const float*)d_in[2];
    const float* gamma = (const float*)d_in[3];
    const float* beta  = (const float*)d_in[4];

    float* y  = (float*)d_out;                       // (8,2048,128)
    float* p2 = (float*)d_out + Bb * Mm * COUT;      // (8,2048,3)

    char*  ws     = (char*)d_ws;
    float* h      = (float*)ws;
    ull*   idxpub = (ull*)(ws + 33619968);
    float* stats  = (float*)(ws + 35717120);
    unsigned int* done = (unsigned int*)(ws + 35718144);

    hipMemsetAsync(stats, 0, 2048, stream);   // stats + done counter
    mega_kernel<<<256, 512, 0, stream>>>(p1, p2, x, W, gamma, beta,
                                         h, stats, done, idxpub, y);
}

// Round 11
// 2045.809 us; speedup vs baseline: 1.5101x; 1.0126x over previous
//
#include <hip/hip_runtime.h>
#include <stdint.h>

#define Bb   8
#define Nn   8192
#define CIN  64
#define COUT 128
#define Mm   2048
#define KNN  16
#define NTOT (Bb*Nn)   // 65536 rows
#define NCONS 248      // consumer blocks

typedef unsigned long long ull;
typedef float v2f __attribute__((ext_vector_type(2)));

#define MAGIC 0x55AA1234u

// ---------------- ws layout (bytes) ----------------
// h        : [0,         33554432)   float 65536x128
// idxpub   : [33619968,  33751040)   ull   8x2048  (magic<<32 | jw)
// stats    : [35717120,  35718144)   float sum[128], sumsq[128]
// done     : [35718144,  35718152)   uint  gemm-done counter
// memset covers [35717120, 35719168).
//
// LDS RULE (R2-R4): static LDS <= 98,816 B per WG.
// SYNC RULE (R8): s_barrier beats LDS spin. (R10): fps wants 4 waves,
// not 8 — barrier join/drain scales with wave count.

__device__ __forceinline__ v2f pk_add(v2f a, v2f b)
{ v2f d; asm("v_pk_add_f32 %0, %1, %2" : "=v"(d) : "v"(a), "v"(b)); return d; }
__device__ __forceinline__ v2f pk_mul(v2f a, v2f b)
{ v2f d; asm("v_pk_mul_f32 %0, %1, %2" : "=v"(d) : "v"(a), "v"(b)); return d; }

// Wave64 float-max reduce (R6/R7-proven).
__device__ __forceinline__ float wave_max16(float x)
{
    int v = __float_as_int(x), t;
    t = __builtin_amdgcn_update_dpp(v, v, 0x111, 0xf, 0xf, false); // row_shr:1
    v = __float_as_int(fmaxf(__int_as_float(v), __int_as_float(t)));
    t = __builtin_amdgcn_update_dpp(v, v, 0x112, 0xf, 0xf, false); // row_shr:2
    v = __float_as_int(fmaxf(__int_as_float(v), __int_as_float(t)));
    t = __builtin_amdgcn_update_dpp(v, v, 0x114, 0xf, 0xf, false); // row_shr:4
    v = __float_as_int(fmaxf(__int_as_float(v), __int_as_float(t)));
    t = __builtin_amdgcn_update_dpp(v, v, 0x118, 0xf, 0xf, false); // row_shr:8
    v = __float_as_int(fmaxf(__int_as_float(v), __int_as_float(t)));
    unsigned r0 = (unsigned)__builtin_amdgcn_readlane(v, 15);
    unsigned r1 = (unsigned)__builtin_amdgcn_readlane(v, 31);
    unsigned r2 = (unsigned)__builtin_amdgcn_readlane(v, 47);
    unsigned r3 = (unsigned)__builtin_amdgcn_readlane(v, 63);
    unsigned m0 = r0 > r1 ? r0 : r1;
    unsigned m1 = r2 > r3 ? r2 : r3;
    unsigned mm = m0 > m1 ? m0 : m1;
    return __uint_as_float(mm);
}

// d2 key for topk (R5-proven): sortable u64, tie -> lower index.
__device__ __forceinline__ ull d2key(
    float qx, float qy, float qz, float qn, float x, float y, float z, int j)
{
    float dot = __fadd_rn(__fadd_rn(__fmul_rn(qx, x), __fmul_rn(qy, y)),
                          __fmul_rn(qz, z));
    float cn  = __fadd_rn(__fadd_rn(__fmul_rn(x, x), __fmul_rn(y, y)),
                          __fmul_rn(z, z));
    float d2  = __fadd_rn(__fsub_rn(qn, __fadd_rn(dot, dot)), cn);
    unsigned int bits = __float_as_uint(d2);
    unsigned int u = bits ^ (((unsigned int)((int)bits >> 31)) | 0x80000000u);
    return ((ull)u << 32) | (unsigned int)j;
}

// ============================================================
// SINGLE MEGAKERNEL (256 blocks x 256 thr, 1/CU co-resident):
//  blocks 0..7   : FPS (4 waves, 32 pts/thread blocked, packed
//                  math). Per iter: argmax -> speculative read of
//                  own winner coords (overlaps DPP+ballot) ->
//                  winner writes {key,coords} slot -> raw
//                  lgkmcnt-only barrier -> ONE LDS round reads
//                  4 keys + 4 coord4s -> cndmask select -> publish
//                  jw (sole global store; p2 written by consumers).
//  blocks 8..255 : Phase A = grid-strided gemm + stats atomics +
//                  done-counter release/acquire; Phase B = fused
//                  kNN + gather + p2out writes (coords from LDS,
//                  bitwise == fps's).
// Deadlock-free: fps never waits; consumers signal before waiting.
// ============================================================
__global__ __launch_bounds__(256, 1)
void mega_kernel(const float* __restrict__ p1, float* __restrict__ p2out,
                 const float* __restrict__ x, const float* __restrict__ W,
                 const float* __restrict__ gamma, const float* __restrict__ beta,
                 float* __restrict__ h, float* __restrict__ stats,
                 unsigned int* done, ull* idxpub, float* __restrict__ y)
{
    __shared__ float px[Nn], py[Nn], pz[Nn];        // 96 KB
    __shared__ ull    skey[2][4];                   // + 64 B
    __shared__ float4 scoord[2][4];                 // + 128 B
    const int tid = threadIdx.x;
    const int w = tid >> 6, lane = tid & 63;

    if (blockIdx.x < 8) {
        // ---------------- FPS path ----------------
        const int b = blockIdx.x;
        const float* pb = p1 + b * Nn * 3;

        for (int i = tid; i < Nn * 3; i += 256) {
            float v = pb[i];
            int pt = i / 3;
            int c  = i - pt * 3;
            if (c == 0) px[pt] = v; else if (c == 1) py[pt] = v; else pz[pt] = v;
        }
        __syncthreads();

        v2f ppx[16], ppy[16], ppz[16], mind[16];
#pragma unroll
        for (int i = 0; i < 16; ++i) {
            int j0 = tid * 32 + 2 * i;               // blocked mapping
            ppx[i] = (v2f){px[j0], px[j0 + 1]};
            ppy[i] = (v2f){py[j0], py[j0 + 1]};
            ppz[i] = (v2f){pz[j0], pz[j0 + 1]};
            mind[i] = (v2f){1e10f, 1e10f};
        }

        float lx = px[0], ly = py[0], lz = pz[0];
        if (tid == 0) {
            __hip_atomic_store(&idxpub[b * Mm], ((ull)MAGIC << 32) | 0ull,
                               __ATOMIC_RELAXED, __HIP_MEMORY_SCOPE_AGENT);
        }

        for (int m = 1; m < Mm; ++m) {
            const int buf = m & 1;
            float nx = -lx, ny = -ly, nz = -lz;     // exact sign flip
            v2f nx2 = (v2f){nx, nx}, ny2 = (v2f){ny, ny}, nz2 = (v2f){nz, nz};
            float bv0 = -1.0f, bv1 = -1.0f; int bj0 = 0, bj1 = 1;
#pragma unroll
            for (int i = 0; i < 16; ++i) {
                v2f dx = pk_add(ppx[i], nx2);       // == ppx - lx, bitwise
                v2f dy = pk_add(ppy[i], ny2);
                v2f dz = pk_add(ppz[i], nz2);
                v2f s  = pk_add(pk_add(pk_mul(dx, dx), pk_mul(dy, dy)),
                                pk_mul(dz, dz));    // ((dx2+dy2)+dz2)
                float m0 = fminf(mind[i].x, s.x);
                float m1 = fminf(mind[i].y, s.y);
                mind[i].x = m0; mind[i].y = m1;
                if (m0 > bv0) { bv0 = m0; bj0 = 2 * i; }
                if (m1 > bv1) { bv1 = m1; bj1 = 2 * i + 1; }
            }
            float bestv; int bestj;
            if (bv1 > bv0 || (bv1 == bv0 && bj1 < bj0)) { bestv = bv1; bestj = bj1; }
            else                                        { bestv = bv0; bestj = bj0; }
            bestj += tid * 32;

            // speculative own-winner coord read; latency overlaps DPP+ballot
            float sx = px[bestj], sy = py[bestj], sz = pz[bestj];

            float wv = wave_max16(bestv);
            ull tie = __ballot(bestv == wv);
            int low = __ffsll((long long)tie) - 1;   // lowest lane = lowest index
            if (lane == low) {
                skey[buf][w] = ((ull)__float_as_uint(wv) << 32) |
                               (unsigned int)(~(unsigned int)bestj);
                scoord[buf][w] = make_float4(sx, sy, sz, 0.0f);
            }
            // LDS-visibility-only barrier (skip __syncthreads' vmcnt drain)
            asm volatile("s_waitcnt lgkmcnt(0)\n\ts_barrier" ::: "memory");

            ull k0 = skey[buf][0], k1 = skey[buf][1];
            ull k2 = skey[buf][2], k3 = skey[buf][3];
            float4 q0 = scoord[buf][0], q1 = scoord[buf][1];
            float4 q2 = scoord[buf][2], q3 = scoord[buf][3];
            bool s1 = k1 > k0;
            ull ka = s1 ? k1 : k0;
            float ax = s1 ? q1.x : q0.x, ay = s1 ? q1.y : q0.y, az = s1 ? q1.z : q0.z;
            bool s2 = k3 > k2;
            ull kb = s2 ? k3 : k2;
            float bx = s2 ? q3.x : q2.x, by = s2 ? q3.y : q2.y, bz = s2 ? q3.z : q2.z;
            bool s3 = kb > ka;
            ull fk = s3 ? kb : ka;
            lx = s3 ? bx : ax; ly = s3 ? by : ay; lz = s3 ? bz : az;
            int jw = (int)(~(unsigned int)fk);
            if (tid == 0) {
                __hip_atomic_store(&idxpub[b * Mm + m],
                                   ((ull)MAGIC << 32) | (ull)(unsigned)jw,
                                   __ATOMIC_RELAXED, __HIP_MEMORY_SCOPE_AGENT);
            }
        }
        return;
    }

    // ============== consumer: Phase A = gemm + stats ==============
    const int cb = blockIdx.x - 8;      // 0..247
    const int cp = lane;                // channel pair = 2cp, 2cp+1
    {
        const float4* w0 = (const float4*)(W + (cp * 2) * CIN);
        const float4* w1 = (const float4*)(W + (cp * 2 + 1) * CIN);
        float s0 = 0.f, s1 = 0.f, q0 = 0.f, q1 = 0.f;
        for (int r0 = cb * 16 + w * 4; r0 < NTOT; r0 += NCONS * 16) {
            const float4* xp = (const float4*)(x + r0 * CIN);
            float a[4][2];
#pragma unroll
            for (int r = 0; r < 4; ++r) { a[r][0] = 0.f; a[r][1] = 0.f; }
#pragma unroll
            for (int k = 0; k < CIN / 4; ++k) {
                float4 wa = w0[k], wb = w1[k];
#pragma unroll
                for (int r = 0; r < 4; ++r) {
                    float4 xv = xp[r * 16 + k];
                    a[r][0] = fmaf(xv.x, wa.x, fmaf(xv.y, wa.y, fmaf(xv.z, wa.z, fmaf(xv.w, wa.w, a[r][0]))));
                    a[r][1] = fmaf(xv.x, wb.x, fmaf(xv.y, wb.y, fmaf(xv.z, wb.z, fmaf(xv.w, wb.w, a[r][1]))));
                }
            }
#pragma unroll
            for (int r = 0; r < 4; ++r) {
                *(float2*)(h + (r0 + r) * COUT + cp * 2) = make_float2(a[r][0], a[r][1]);
                s0 += a[r][0]; s1 += a[r][1];
                q0 = fmaf(a[r][0], a[r][0], q0); q1 = fmaf(a[r][1], a[r][1], q1);
            }
        }
        float4* comb = (float4*)px;                  // [4][64], restaged later
        comb[w * 64 + cp] = make_float4(s0, s1, q0, q1);
        __syncthreads();
        if (tid < 64) {
            float4 t = comb[cp];
#pragma unroll
            for (int j = 1; j < 4; ++j) {
                float4 o = comb[j * 64 + cp];
                t.x += o.x; t.y += o.y; t.z += o.z; t.w += o.w;
            }
            atomicAdd(&stats[2 * cp], t.x);       atomicAdd(&stats[2 * cp + 1], t.y);
            atomicAdd(&stats[128 + 2 * cp], t.z); atomicAdd(&stats[128 + 2 * cp + 1], t.w);
        }
        __syncthreads();
        if (tid == 0) {
            __hip_atomic_fetch_add(done, 1u, __ATOMIC_RELEASE,
                                   __HIP_MEMORY_SCOPE_AGENT);
            while (__hip_atomic_load(done, __ATOMIC_ACQUIRE,
                                     __HIP_MEMORY_SCOPE_AGENT) < NCONS)
                __builtin_amdgcn_s_sleep(2);
        }
        __syncthreads();   // all h stores + stats adds now visible
    }

    // per-lane BN scale/bias (same formula as proven finalize)
    float sc0, sc1, bi0, bi1;
    {
        float mean0 = stats[2 * cp] * (1.0f / 65536.0f);
        float mean1 = stats[2 * cp + 1] * (1.0f / 65536.0f);
        float var0  = stats[128 + 2 * cp] * (1.0f / 65536.0f) - mean0 * mean0;
        float var1  = stats[128 + 2 * cp + 1] * (1.0f / 65536.0f) - mean1 * mean1;
        sc0 = gamma[2 * cp] / sqrtf(var0 + 1e-5f);
        sc1 = gamma[2 * cp + 1] / sqrtf(var1 + 1e-5f);
        bi0 = beta[2 * cp] - mean0 * sc0;
        bi1 = beta[2 * cp + 1] - mean1 * sc1;
    }

    // ============== consumer: Phase B = fused kNN + gather + p2 ==============
    const int b = cb / 31;              // 31 blocks per batch
    const int k = cb - b * 31;          // query residue mod 31
    const float* pb = p1 + b * Nn * 3;

    for (int i = tid; i < Nn * 3; i += 256) {
        float v = pb[i];
        int pt = i / 3;
        int c  = i - pt * 3;
        if (c == 0) px[pt] = v; else if (c == 1) py[pt] = v; else pz[pt] = v;
    }
    __syncthreads();

    const int c0 = lane * 2;
    const ull INV = ~0ull;

    for (int t = w; k + 31 * t < Mm; t += 4) {
        const int m = k + 31 * t;
        const int qrow = b * Mm + m;

        ull pv;
        for (;;) {
            pv = __hip_atomic_load(&idxpub[qrow], __ATOMIC_RELAXED,
                                   __HIP_MEMORY_SCOPE_AGENT);
            if ((unsigned)(pv >> 32) == MAGIC) break;
            __builtin_amdgcn_s_sleep(2);
        }
        const int jq = (int)(pv & 0x1FFFull);
        const float qx = px[jq], qy = py[jq], qz = pz[jq];
        if (lane == 0) {   // p2 output (bitwise == p1 coords)
            p2out[qrow * 3]     = qx;
            p2out[qrow * 3 + 1] = qy;
            p2out[qrow * 3 + 2] = qz;
        }
        const float qn = __fadd_rn(__fadd_rn(__fmul_rn(qx, qx), __fmul_rn(qy, qy)),
                                   __fmul_rn(qz, qz));

        ull k1 = INV, k2 = INV, k3 = INV;
#pragma unroll 4
        for (int i = 0; i < 128; ++i) {
            int j = lane + (i << 6);
            ull key = d2key(qx, qy, qz, qn, px[j], py[j], pz[j], j);
            bool b1 = key < k1, b2 = key < k2, b3 = key < k3;
            ull n1 = b1 ? key : k1;
            ull n2 = b1 ? k1 : (b2 ? key : k2);
            ull n3 = b2 ? k2 : (b3 ? key : k3);
            k1 = n1; k2 = n2; k3 = n3;
        }

        float a0 = -1e30f, a1 = -1e30f;
        for (int r = 0; r < KNN; ++r) {
            ull wk = k1;
#pragma unroll
            for (int off = 1; off < 64; off <<= 1) {
                ull ok = __shfl_xor(wk, off, 64);
                wk = ok < wk ? ok : wk;
            }
            const int n = (int)(unsigned int)(wk & 0xFFFFFFFFull);
            const float2 v = *(const float2*)(h + (((b << 13) + n) * COUT) + c0);
            if (k1 == wk) { k1 = k2; k2 = k3; k3 = INV; }
            if (k1 == INV) {   // rare: rebuild top-3 among keys > wk
                for (int i = 0; i < 128; ++i) {
                    int j = lane + (i << 6);
                    ull key = d2key(qx, qy, qz, qn, px[j], py[j], pz[j], j);
                    if (key > wk) {
                        bool b1 = key < k1, b2 = key < k2, b3 = key < k3;
                        ull n1 = b1 ? key : k1;
                        ull n2 = b1 ? k1 : (b2 ? key : k2);
                        ull n3 = b2 ? k2 : (b3 ? key : k3);
                        k1 = n1; k2 = n2; k3 = n3;
                    }
                }
            }
            a0 = fmaxf(a0, fmaf(v.x, sc0, bi0));
            a1 = fmaxf(a1, fmaf(v.y, sc1, bi1));
        }
        a0 = fmaxf(a0, 0.0f); a1 = fmaxf(a1, 0.0f);
        *(float2*)(y + qrow * COUT + c0) = make_float2(a0, a1);
    }
}

extern "C" void kernel_launch(void* const* d_in, const int* in_sizes, int n_in,
                              void* d_out, int out_size, void* d_ws, size_t ws_size,
                              hipStream_t stream)
{
    const float* x     = (const float*)d_in[0];
    const float* p1    = (const float*)d_in[1];
    const float* W     = (const float*)d_in[2];
    const float* gamma = (const float*)d_in[3];
    const float* beta  = (const float*)d_in[4];

    float* y  = (float*)d_out;                       // (8,2048,128)
    float* p2 = (float*)d_out + Bb * Mm * COUT;      // (8,2048,3)

    char*  ws     = (char*)d_ws;
    float* h      = (float*)ws;
    ull*   idxpub = (ull*)(ws + 33619968);
    float* stats  = (float*)(ws + 35717120);
    unsigned int* done = (unsigned int*)(ws + 35718144);

    hipMemsetAsync(stats, 0, 2048, stream);   // stats + done counter
    mega_kernel<<<256, 256, 0, stream>>>(p1, p2, x, W, gamma, beta,
                                         h, stats, done, idxpub, y);
}

// Round 12
// 1902.074 us; speedup vs baseline: 1.6242x; 1.0756x over previous
//
#include <hip/hip_runtime.h>
#include <stdint.h>

#define Bb   8
#define Nn   8192
#define CIN  64
#define COUT 128
#define Mm   2048
#define KNN  16
#define NTOT (Bb*Nn)   // 65536 rows
#define NCONS 248      // consumer blocks

typedef unsigned long long ull;
typedef float v2f __attribute__((ext_vector_type(2)));

#define MAGIC 0x55AA1234u

// ---------------- ws layout (bytes) ----------------
// h        : [0,         33554432)   float 65536x128
// idxpub   : [33619968,  33751040)   ull   8x2048  (magic<<32 | jw)
// stats    : [35717120,  35718144)   float sum[128], sumsq[128]
// done     : [35718144,  35718148)   uint  gemm-done counter
// initflag : [35718148,  35718152)   uint  MAGIC once stats/done zeroed
// No memset: block 8 zeroes stats+done, then release-stores initflag;
// consumers acquire-spin initflag before their atomics. idxpub is
// poison-safe via MAGIC tag compare.
//
// LDS RULE (R2-R4): static LDS <= 98,816 B per WG.
// SYNC RULE (R8): s_barrier beats LDS spin. (R10): fps wants 4 waves.
// (R11): divergent LDS gather loses to uniform broadcast — reverted.

__device__ __forceinline__ v2f pk_add(v2f a, v2f b)
{ v2f d; asm("v_pk_add_f32 %0, %1, %2" : "=v"(d) : "v"(a), "v"(b)); return d; }
__device__ __forceinline__ v2f pk_mul(v2f a, v2f b)
{ v2f d; asm("v_pk_mul_f32 %0, %1, %2" : "=v"(d) : "v"(a), "v"(b)); return d; }

// Wave64 float-max reduce (R6/R7-proven).
__device__ __forceinline__ float wave_max16(float x)
{
    int v = __float_as_int(x), t;
    t = __builtin_amdgcn_update_dpp(v, v, 0x111, 0xf, 0xf, false); // row_shr:1
    v = __float_as_int(fmaxf(__int_as_float(v), __int_as_float(t)));
    t = __builtin_amdgcn_update_dpp(v, v, 0x112, 0xf, 0xf, false); // row_shr:2
    v = __float_as_int(fmaxf(__int_as_float(v), __int_as_float(t)));
    t = __builtin_amdgcn_update_dpp(v, v, 0x114, 0xf, 0xf, false); // row_shr:4
    v = __float_as_int(fmaxf(__int_as_float(v), __int_as_float(t)));
    t = __builtin_amdgcn_update_dpp(v, v, 0x118, 0xf, 0xf, false); // row_shr:8
    v = __float_as_int(fmaxf(__int_as_float(v), __int_as_float(t)));
    unsigned r0 = (unsigned)__builtin_amdgcn_readlane(v, 15);
    unsigned r1 = (unsigned)__builtin_amdgcn_readlane(v, 31);
    unsigned r2 = (unsigned)__builtin_amdgcn_readlane(v, 47);
    unsigned r3 = (unsigned)__builtin_amdgcn_readlane(v, 63);
    unsigned m0 = r0 > r1 ? r0 : r1;
    unsigned m1 = r2 > r3 ? r2 : r3;
    unsigned mm = m0 > m1 ? m0 : m1;
    return __uint_as_float(mm);
}

// d2 key for topk (R5-proven): sortable u64, tie -> lower index.
__device__ __forceinline__ ull d2key(
    float qx, float qy, float qz, float qn, float x, float y, float z, int j)
{
    float dot = __fadd_rn(__fadd_rn(__fmul_rn(qx, x), __fmul_rn(qy, y)),
                          __fmul_rn(qz, z));
    float cn  = __fadd_rn(__fadd_rn(__fmul_rn(x, x), __fmul_rn(y, y)),
                          __fmul_rn(z, z));
    float d2  = __fadd_rn(__fsub_rn(qn, __fadd_rn(dot, dot)), cn);
    unsigned int bits = __float_as_uint(d2);
    unsigned int u = bits ^ (((unsigned int)((int)bits >> 31)) | 0x80000000u);
    return ((ull)u << 32) | (unsigned int)j;
}

// ============================================================
// SINGLE MEGAKERNEL (256 blocks x 256 thr, 1/CU co-resident):
//  blocks 0..7   : FPS, R9-proven body (4 waves, 32 pts/thread
//                  blocked, packed math, DPP+ballot, key-only
//                  slots, __syncthreads, publish jw early, then
//                  uniform px[jw] broadcast). No p2 stores here.
//  blocks 8..255 : block 8 zeroes stats/done + releases initflag.
//                  Phase A = grid-strided gemm + register stats ->
//                  LDS combine -> (acquire initflag) -> atomicAdd
//                  -> done-counter release/acquire. Phase B =
//                  fused kNN + gather + p2out writes.
// Deadlock-free: fps never waits; consumers signal before waiting.
// ============================================================
__global__ __launch_bounds__(256, 1)
void mega_kernel(const float* __restrict__ p1, float* __restrict__ p2out,
                 const float* __restrict__ x, const float* __restrict__ W,
                 const float* __restrict__ gamma, const float* __restrict__ beta,
                 float* __restrict__ h, float* __restrict__ stats,
                 unsigned int* done, unsigned int* initflag,
                 ull* idxpub, float* __restrict__ y)
{
    __shared__ float px[Nn], py[Nn], pz[Nn];        // 96 KB
    __shared__ alignas(16) ull wkey[2][4];          // + 64 B
    const int tid = threadIdx.x;
    const int w = tid >> 6, lane = tid & 63;

    if (blockIdx.x < 8) {
        // ---------------- FPS path (R9-proven body) ----------------
        const int b = blockIdx.x;
        const float* pb = p1 + b * Nn * 3;

        for (int i = tid; i < Nn * 3; i += 256) {
            float v = pb[i];
            int pt = i / 3;
            int c  = i - pt * 3;
            if (c == 0) px[pt] = v; else if (c == 1) py[pt] = v; else pz[pt] = v;
        }
        __syncthreads();

        v2f ppx[16], ppy[16], ppz[16], mind[16];
#pragma unroll
        for (int i = 0; i < 16; ++i) {
            int j0 = tid * 32 + 2 * i;               // blocked mapping
            ppx[i] = (v2f){px[j0], px[j0 + 1]};
            ppy[i] = (v2f){py[j0], py[j0 + 1]};
            ppz[i] = (v2f){pz[j0], pz[j0 + 1]};
            mind[i] = (v2f){1e10f, 1e10f};
        }

        float lx = px[0], ly = py[0], lz = pz[0];
        if (tid == 0) {
            __hip_atomic_store(&idxpub[b * Mm], ((ull)MAGIC << 32) | 0ull,
                               __ATOMIC_RELAXED, __HIP_MEMORY_SCOPE_AGENT);
        }

        for (int m = 1; m < Mm; ++m) {
            const int buf = m & 1;
            float nx = -lx, ny = -ly, nz = -lz;     // exact sign flip
            v2f nx2 = (v2f){nx, nx}, ny2 = (v2f){ny, ny}, nz2 = (v2f){nz, nz};
            float bv0 = -1.0f, bv1 = -1.0f; int bj0 = 0, bj1 = 1;
#pragma unroll
            for (int i = 0; i < 16; ++i) {
                v2f dx = pk_add(ppx[i], nx2);       // == ppx - lx, bitwise
                v2f dy = pk_add(ppy[i], ny2);
                v2f dz = pk_add(ppz[i], nz2);
                v2f s  = pk_add(pk_add(pk_mul(dx, dx), pk_mul(dy, dy)),
                                pk_mul(dz, dz));    // ((dx2+dy2)+dz2)
                float m0 = fminf(mind[i].x, s.x);
                float m1 = fminf(mind[i].y, s.y);
                mind[i].x = m0; mind[i].y = m1;
                if (m0 > bv0) { bv0 = m0; bj0 = 2 * i; }
                if (m1 > bv1) { bv1 = m1; bj1 = 2 * i + 1; }
            }
            float bestv; int bestj;
            if (bv1 > bv0 || (bv1 == bv0 && bj1 < bj0)) { bestv = bv1; bestj = bj1; }
            else                                        { bestv = bv0; bestj = bj0; }
            bestj += tid * 32;

            float wv = wave_max16(bestv);
            ull tie = __ballot(bestv == wv);
            int low = __ffsll((long long)tie) - 1;   // lowest lane = lowest index
            if (lane == low) {
                wkey[buf][w] = ((ull)__float_as_uint(wv) << 32) |
                               (unsigned int)(~(unsigned int)bestj);
            }
            __syncthreads();

            ull k0 = wkey[buf][0], k1 = wkey[buf][1];
            ull k2 = wkey[buf][2], k3 = wkey[buf][3];
            ull k01 = k0 > k1 ? k0 : k1;
            ull k23 = k2 > k3 ? k2 : k3;
            ull fk  = k01 > k23 ? k01 : k23;
            int jw = (int)(~(unsigned int)fk);
            if (tid == 0) {   // publish early; ack hides under next compute
                __hip_atomic_store(&idxpub[b * Mm + m],
                                   ((ull)MAGIC << 32) | (ull)(unsigned)jw,
                                   __ATOMIC_RELAXED, __HIP_MEMORY_SCOPE_AGENT);
            }
            lx = px[jw]; ly = py[jw]; lz = pz[jw];   // uniform broadcast reads
        }
        return;
    }

    // ============== consumer: init + Phase A = gemm + stats ==============
    const int cb = blockIdx.x - 8;      // 0..247
    const int cp = lane;                // channel pair = 2cp, 2cp+1

    if (blockIdx.x == 8) {              // zero stats/done, release initflag
        if (tid < 256) stats[tid] = 0.0f;
        if (tid == 0) *done = 0u;
        __syncthreads();
        if (tid == 0)
            __hip_atomic_store(initflag, MAGIC, __ATOMIC_RELEASE,
                               __HIP_MEMORY_SCOPE_AGENT);
    }

    {
        const float4* w0 = (const float4*)(W + (cp * 2) * CIN);
        const float4* w1 = (const float4*)(W + (cp * 2 + 1) * CIN);
        float s0 = 0.f, s1 = 0.f, q0 = 0.f, q1 = 0.f;
        for (int r0 = cb * 16 + w * 4; r0 < NTOT; r0 += NCONS * 16) {
            const float4* xp = (const float4*)(x + r0 * CIN);
            float a[4][2];
#pragma unroll
            for (int r = 0; r < 4; ++r) { a[r][0] = 0.f; a[r][1] = 0.f; }
#pragma unroll
            for (int k = 0; k < CIN / 4; ++k) {
                float4 wa = w0[k], wb = w1[k];
#pragma unroll
                for (int r = 0; r < 4; ++r) {
                    float4 xv = xp[r * 16 + k];
                    a[r][0] = fmaf(xv.x, wa.x, fmaf(xv.y, wa.y, fmaf(xv.z, wa.z, fmaf(xv.w, wa.w, a[r][0]))));
                    a[r][1] = fmaf(xv.x, wb.x, fmaf(xv.y, wb.y, fmaf(xv.z, wb.z, fmaf(xv.w, wb.w, a[r][1]))));
                }
            }
#pragma unroll
            for (int r = 0; r < 4; ++r) {
                *(float2*)(h + (r0 + r) * COUT + cp * 2) = make_float2(a[r][0], a[r][1]);
                s0 += a[r][0]; s1 += a[r][1];
                q0 = fmaf(a[r][0], a[r][0], q0); q1 = fmaf(a[r][1], a[r][1], q1);
            }
        }
        float4* comb = (float4*)px;                  // [4][64], restaged later
        comb[w * 64 + cp] = make_float4(s0, s1, q0, q1);
        __syncthreads();
        if (tid == 0) {    // wait for stats zeroed (block 8; long done by now)
            while (__hip_atomic_load(initflag, __ATOMIC_ACQUIRE,
                                     __HIP_MEMORY_SCOPE_AGENT) != MAGIC)
                __builtin_amdgcn_s_sleep(2);
        }
        __syncthreads();
        if (tid < 64) {
            float4 t = comb[cp];
#pragma unroll
            for (int j = 1; j < 4; ++j) {
                float4 o = comb[j * 64 + cp];
                t.x += o.x; t.y += o.y; t.z += o.z; t.w += o.w;
            }
            atomicAdd(&stats[2 * cp], t.x);       atomicAdd(&stats[2 * cp + 1], t.y);
            atomicAdd(&stats[128 + 2 * cp], t.z); atomicAdd(&stats[128 + 2 * cp + 1], t.w);
        }
        __syncthreads();
        if (tid == 0) {
            __hip_atomic_fetch_add(done, 1u, __ATOMIC_RELEASE,
                                   __HIP_MEMORY_SCOPE_AGENT);
            while (__hip_atomic_load(done, __ATOMIC_ACQUIRE,
                                     __HIP_MEMORY_SCOPE_AGENT) < NCONS)
                __builtin_amdgcn_s_sleep(2);
        }
        __syncthreads();   // all h stores + stats adds now visible
    }

    // per-lane BN scale/bias (same formula as proven finalize)
    float sc0, sc1, bi0, bi1;
    {
        float mean0 = stats[2 * cp] * (1.0f / 65536.0f);
        float mean1 = stats[2 * cp + 1] * (1.0f / 65536.0f);
        float var0  = stats[128 + 2 * cp] * (1.0f / 65536.0f) - mean0 * mean0;
        float var1  = stats[128 + 2 * cp + 1] * (1.0f / 65536.0f) - mean1 * mean1;
        sc0 = gamma[2 * cp] / sqrtf(var0 + 1e-5f);
        sc1 = gamma[2 * cp + 1] / sqrtf(var1 + 1e-5f);
        bi0 = beta[2 * cp] - mean0 * sc0;
        bi1 = beta[2 * cp + 1] - mean1 * sc1;
    }

    // ============== consumer: Phase B = fused kNN + gather + p2 ==============
    const int b = cb / 31;              // 31 blocks per batch
    const int k = cb - b * 31;          // query residue mod 31
    const float* pb = p1 + b * Nn * 3;

    for (int i = tid; i < Nn * 3; i += 256) {
        float v = pb[i];
        int pt = i / 3;
        int c  = i - pt * 3;
        if (c == 0) px[pt] = v; else if (c == 1) py[pt] = v; else pz[pt] = v;
    }
    __syncthreads();

    const int c0 = lane * 2;
    const ull INV = ~0ull;

    for (int t = w; k + 31 * t < Mm; t += 4) {
        const int m = k + 31 * t;
        const int qrow = b * Mm + m;

        ull pv;
        for (;;) {
            pv = __hip_atomic_load(&idxpub[qrow], __ATOMIC_RELAXED,
                                   __HIP_MEMORY_SCOPE_AGENT);
            if ((unsigned)(pv >> 32) == MAGIC) break;
            __builtin_amdgcn_s_sleep(2);
        }
        const int jq = (int)(pv & 0x1FFFull);
        const float qx = px[jq], qy = py[jq], qz = pz[jq];
        if (lane == 0) {   // p2 output (bitwise == p1 coords)
            p2out[qrow * 3]     = qx;
            p2out[qrow * 3 + 1] = qy;
            p2out[qrow * 3 + 2] = qz;
        }
        const float qn = __fadd_rn(__fadd_rn(__fmul_rn(qx, qx), __fmul_rn(qy, qy)),
                                   __fmul_rn(qz, qz));

        ull k1 = INV, k2 = INV, k3 = INV;
#pragma unroll 4
        for (int i = 0; i < 128; ++i) {
            int j = lane + (i << 6);
            ull key = d2key(qx, qy, qz, qn, px[j], py[j], pz[j], j);
            bool b1 = key < k1, b2 = key < k2, b3 = key < k3;
            ull n1 = b1 ? key : k1;
            ull n2 = b1 ? k1 : (b2 ? key : k2);
            ull n3 = b2 ? k2 : (b3 ? key : k3);
            k1 = n1; k2 = n2; k3 = n3;
        }

        float a0 = -1e30f, a1 = -1e30f;
        for (int r = 0; r < KNN; ++r) {
            ull wk = k1;
#pragma unroll
            for (int off = 1; off < 64; off <<= 1) {
                ull ok = __shfl_xor(wk, off, 64);
                wk = ok < wk ? ok : wk;
            }
            const int n = (int)(unsigned int)(wk & 0xFFFFFFFFull);
            const float2 v = *(const float2*)(h + (((b << 13) + n) * COUT) + c0);
            if (k1 == wk) { k1 = k2; k2 = k3; k3 = INV; }
            if (k1 == INV) {   // rare: rebuild top-3 among keys > wk
                for (int i = 0; i < 128; ++i) {
                    int j = lane + (i << 6);
                    ull key = d2key(qx, qy, qz, qn, px[j], py[j], pz[j], j);
                    if (key > wk) {
                        bool b1 = key < k1, b2 = key < k2, b3 = key < k3;
                        ull n1 = b1 ? key : k1;
                        ull n2 = b1 ? k1 : (b2 ? key : k2);
                        ull n3 = b2 ? k2 : (b3 ? key : k3);
                        k1 = n1; k2 = n2; k3 = n3;
                    }
                }
            }
            a0 = fmaxf(a0, fmaf(v.x, sc0, bi0));
            a1 = fmaxf(a1, fmaf(v.y, sc1, bi1));
        }
        a0 = fmaxf(a0, 0.0f); a1 = fmaxf(a1, 0.0f);
        *(float2*)(y + qrow * COUT + c0) = make_float2(a0, a1);
    }
}

extern "C" void kernel_launch(void* const* d_in, const int* in_sizes, int n_in,
                              void* d_out, int out_size, void* d_ws, size_t ws_size,
                              hipStream_t stream)
{
    const float* x     = (const float*)d_in[0];
    const float* p1    = (const float*)d_in[1];
    const float* W     = (const float*)d_in[2];
    const float* gamma = (const float*)d_in[3];
    const float* beta  = (const float*)d_in[4];

    float* y  = (float*)d_out;                       // (8,2048,128)
    float* p2 = (float*)d_out + Bb * Mm * COUT;      // (8,2048,3)

    char*  ws     = (char*)d_ws;
    float* h      = (float*)ws;
    ull*   idxpub = (ull*)(ws + 33619968);
    float* stats  = (float*)(ws + 35717120);
    unsigned int* done     = (unsigned int*)(ws + 35718144);
    unsigned int* initflag = (unsigned int*)(ws + 35718148);

    mega_kernel<<<256, 256, 0, stream>>>(p1, p2, x, W, gamma, beta,
                                         h, stats, done, initflag, idxpub, y);
}